// Round 5
// baseline (419.513 us; speedup 1.0000x reference)
//
#include <hip/hip_runtime.h>

#define HD 14
#define NOUT 2
#define NN 200000
#define EE 3200000
#define GG 2000

// bucket config
#define WNODE 128                         // nodes per bucket (d >> 7)
#define NBIN 1563                         // ceil(200000/128)
#define NBLKA 256                         // partition blocks
#define EPERA 12500                       // edges per partition block (256*12500 = E)
#define NCELL (NBIN*NBLKA)                // 400128

// scan config
#define SBS 256
#define SEL 8
#define CHUNK (SBS*SEL)                   // 2048
#define NBSCAN ((NCELL + CHUNK - 1) / CHUNK)  // 196

__device__ __forceinline__ float psi_f(float v) {
    float r = log1pf(fabsf(v));
    return v < 0.f ? -r : r;
}

__device__ __forceinline__ void stage_f(float* dst, const float* src, int n) {
    for (int i = threadIdx.x; i < n; i += blockDim.x) dst[i] = src[i];
}

__device__ __forceinline__ int lower_bound_i(const int* a, int n, int key) {
    int lo = 0, hi = n;
    while (lo < hi) { int mid = (lo + hi) >> 1; if (a[mid] < key) lo = mid + 1; else hi = mid; }
    return lo;
}

// ---- pass 0: fold We2 into Wn11 ----
// C[k][j] = sum_t We2[k][t]*Wn11[1+t][j];  bp[j] = bn11[j] + sum_t be2[t]*Wn11[1+t][j]
__global__ void __launch_bounds__(256)
fold_kernel(const float* __restrict__ We2, const float* __restrict__ be2,
            const float* __restrict__ Wn11, const float* __restrict__ bn11,
            float* __restrict__ C, float* __restrict__ bp)
{
    int t = threadIdx.x;
    if (t < HD*HD) {
        int k = t / HD, j = t % HD;
        float s = 0.f;
        #pragma unroll
        for (int u = 0; u < HD; ++u) s = fmaf(We2[k*HD+u], Wn11[(1+u)*HD+j], s);
        C[t] = s;
    } else if (t < HD*HD + HD) {
        int j = t - HD*HD;
        float s = bn11[j];
        #pragma unroll
        for (int u = 0; u < HD; ++u) s = fmaf(be2[u], Wn11[(1+u)*HD+j], s);
        bp[j] = s;
    }
}

// ---- pass 1: per-(bucket, block) histogram of col>>7, bin-major output ----
__global__ void __launch_bounds__(256)
histA(const int* __restrict__ col, int* __restrict__ ghist)
{
    __shared__ int hist[NBIN];
    int tid = threadIdx.x;
    for (int i = tid; i < NBIN; i += 256) hist[i] = 0;
    __syncthreads();
    int j = blockIdx.x;
    int base = j * EPERA;
    for (int it = 0; it < EPERA; it += 256) {
        int o = it + tid;
        if (o < EPERA) atomicAdd(&hist[col[base + o] >> 7], 1);
    }
    __syncthreads();
    for (int i = tid; i < NBIN; i += 256) ghist[i * NBLKA + j] = hist[i];
}

// ---- scan of ghist[NCELL] -> excl (chunk-local) + btot (chunk bases) ----
__global__ void __launch_bounds__(SBS)
scan1_kernel(const int* __restrict__ cnt, int* __restrict__ excl,
             int* __restrict__ btot, int n)
{
    __shared__ int lds[SBS];
    int tid = threadIdx.x;
    int base = blockIdx.x * CHUNK + tid * SEL;
    int v[SEL]; int s = 0;
    #pragma unroll
    for (int k = 0; k < SEL; ++k) { int i = base + k; v[k] = (i < n) ? cnt[i] : 0; s += v[k]; }
    lds[tid] = s; __syncthreads();
    for (int off = 1; off < SBS; off <<= 1) {
        int t = (tid >= off) ? lds[tid - off] : 0;
        __syncthreads();
        lds[tid] += t;
        __syncthreads();
    }
    int incl = lds[tid];
    int run = incl - s;
    if (tid == SBS - 1) btot[blockIdx.x] = incl;
    #pragma unroll
    for (int k = 0; k < SEL; ++k) { int i = base + k; if (i < n) excl[i] = run; run += v[k]; }
}

__global__ void __launch_bounds__(256)
scan2_kernel(int* __restrict__ btot, int nb)
{
    __shared__ int lds[256];
    int tid = threadIdx.x;
    int v = (tid < nb) ? btot[tid] : 0;
    lds[tid] = v; __syncthreads();
    for (int off = 1; off < 256; off <<= 1) {
        int t = (tid >= off) ? lds[tid - off] : 0;
        __syncthreads();
        lds[tid] += t;
        __syncthreads();
    }
    if (tid < nb) btot[tid] = lds[tid] - v;   // exclusive chunk bases, in place
}

// ---- pass 2: partition edges into buckets (LDS ranking, no global atomics) ----
__global__ void __launch_bounds__(256)
scatterA(const int* __restrict__ row, const int* __restrict__ col,
         const int* __restrict__ excl, const int* __restrict__ btot,
         int2* __restrict__ srcdst)
{
    __shared__ int lcount[NBIN];
    int tid = threadIdx.x;
    for (int i = tid; i < NBIN; i += 256) lcount[i] = 0;
    __syncthreads();
    int j = blockIdx.x;
    int base = j * EPERA;
    for (int it = 0; it < EPERA; it += 256) {
        int o = it + tid;
        if (o < EPERA) {
            int e = base + o;
            int c = col[e];
            int r = row[e];
            int bb = c >> 7;
            int rk = atomicAdd(&lcount[bb], 1);
            int cell = bb * NBLKA + j;
            int pos = excl[cell] + btot[cell >> 11] + rk;
            srcdst[pos] = make_int2(r, c);
        }
    }
}

// ---- pass 3: per-bucket fused edge compute + LDS aggregation + node MLP ----
__global__ void __launch_bounds__(256)
bucket_kernel(const float4* __restrict__ x,
              const int2* __restrict__ srcdst,
              const int* __restrict__ excl, const int* __restrict__ btot,
              const float* __restrict__ We1, const float* __restrict__ be1,
              const float* __restrict__ Wn11,    // row 0 used
              const float* __restrict__ C, const float* __restrict__ bp,
              const float* __restrict__ Wn12, const float* __restrict__ bn12,
              const float* __restrict__ Wn21, const float* __restrict__ bn21,
              const float* __restrict__ Wn22, const float* __restrict__ bn22,
              float* __restrict__ x_out, int N, int E)
{
    __shared__ float sWe1[4*HD], sbe1[HD], sW11[HD], sC[HD*HD], sbp[HD];
    __shared__ float sW12[HD*HD], sb12[HD], sW21[(1+HD)*HD], sb21[HD], sW22[HD*HD], sb22[HD];
    __shared__ float xn[WNODE][4];
    __shared__ float nip[WNODE], nf2[WNODE];
    __shared__ float aggs[WNODE][15];
    __shared__ int   degs[WNODE];

    int tid = threadIdx.x;
    stage_f(sWe1, We1, 4*HD);  stage_f(sbe1, be1, HD);
    stage_f(sW11, Wn11, HD);   stage_f(sC, C, HD*HD);   stage_f(sbp, bp, HD);
    stage_f(sW12, Wn12, HD*HD); stage_f(sb12, bn12, HD);
    stage_f(sW21, Wn21, (1+HD)*HD); stage_f(sb21, bn21, HD);
    stage_f(sW22, Wn22, HD*HD); stage_f(sb22, bn22, HD);

    for (int i = tid; i < WNODE*15; i += 256) ((float*)aggs)[i] = 0.f;
    for (int i = tid; i < WNODE; i += 256) degs[i] = 0;

    int b = blockIdx.x;
    int nb0 = b * WNODE;
    int nN = min(WNODE, N - nb0);

    if (tid < nN) {
        float4 v = x[nb0 + tid];
        xn[tid][0] = v.x; xn[tid][1] = v.y; xn[tid][2] = v.z; xn[tid][3] = v.w;
        float ip = -v.x*v.x + v.y*v.y + v.z*v.z + v.w*v.w;
        nip[tid] = ip;
        nf2[tid] = psi_f(ip);
    }
    __syncthreads();

    int lo = excl[b * NBLKA] + btot[(b * NBLKA) >> 11];
    int hi = (b + 1 < NBIN) ? (excl[(b+1) * NBLKA] + btot[((b+1) * NBLKA) >> 11]) : E;

    for (int base = lo; base < hi; base += 256) {
        int i = base + tid;
        if (i < hi) {
            int2 sd = srcdst[i];
            int s  = sd.x;
            int dl = sd.y - nb0;

            float4 a = x[s];
            float bx = xn[dl][0], by = xn[dl][1], bz = xn[dl][2], bw = xn[dl][3];

            float f0 = -a.x*a.x + a.y*a.y + a.z*a.z + a.w*a.w;
            float f1 = -a.x*bx + a.y*by + a.z*bz + a.w*bw;
            float dx = a.x-bx, dy = a.y-by, dz = a.z-bz, dw = a.w-bw;
            float f3 = psi_f(-dx*dx + dy*dy + dz*dz + dw*dw);
            float f2 = nf2[dl];

            float h1[HD];
            #pragma unroll
            for (int j = 0; j < HD; ++j) {
                float v = f0*sWe1[j] + f1*sWe1[HD+j] + f2*sWe1[2*HD+j] + f3*sWe1[3*HD+j] + sbe1[j];
                h1[j] = fmaxf(v, 0.f);
            }
            #pragma unroll
            for (int j = 0; j < HD; ++j) {
                float v = fmaf(f0, sW11[j], sbp[j]);
                #pragma unroll
                for (int k = 0; k < HD; ++k) v = fmaf(h1[k], sC[k*HD+j], v);
                atomicAdd(&aggs[dl][j], fmaxf(v, 0.f));    // h2, summed per node
            }
            atomicAdd(&degs[dl], 1);
        }
    }
    __syncthreads();

    if (tid < nN) {
        int deg = degs[tid];
        float aggm[HD];
        if (deg > 0) {
            float inv = 1.0f / (float)deg;
            float am[HD];
            #pragma unroll
            for (int k = 0; k < HD; ++k) am[k] = aggs[tid][k] * inv;
            #pragma unroll
            for (int j = 0; j < HD; ++j) {
                float v = sb12[j];
                #pragma unroll
                for (int k = 0; k < HD; ++k) v = fmaf(am[k], sW12[k*HD+j], v);
                aggm[j] = v;
            }
        } else {
            #pragma unroll
            for (int j = 0; j < HD; ++j) aggm[j] = 0.f;
        }

        float ipbb = nip[tid];
        float h[HD];
        #pragma unroll
        for (int j = 0; j < HD; ++j) {
            float v = fmaf(ipbb, sW21[j], sb21[j]);
            #pragma unroll
            for (int k = 0; k < HD; ++k) v = fmaf(aggm[k], sW21[(1+k)*HD+j], v);
            h[j] = fmaxf(v, 0.f);
        }
        float xo[16];
        #pragma unroll
        for (int j = 0; j < HD; ++j) {
            float v = sb22[j];
            #pragma unroll
            for (int k = 0; k < HD; ++k) v = fmaf(h[k], sW22[k*HD+j], v);
            xo[j] = v;
        }
        float4* op = (float4*)(x_out + (size_t)(nb0 + tid) * 16);
        op[0] = make_float4(xo[0], xo[1], xo[2], xo[3]);
        op[1] = make_float4(xo[4], xo[5], xo[6], xo[7]);
        op[2] = make_float4(xo[8], xo[9], xo[10], xo[11]);
        op[3] = make_float4(xo[12], xo[13], 0.f, 0.f);
    }
}

// ---- pass 4: per-graph mean (batch sorted -> contiguous ranges) + global MLP ----
__global__ void __launch_bounds__(256)
graph_kernel(const float* __restrict__ x_out, const int* __restrict__ batch,
             const float* __restrict__ Wg1, const float* __restrict__ bg1,
             const float* __restrict__ Wg2, const float* __restrict__ bg2,
             float* __restrict__ out, int N, int G)
{
    __shared__ float red[256 * 15];
    int g = blockIdx.x;
    int tid = threadIdx.x;

    int lo = lower_bound_i(batch, N, g);
    int hi = lower_bound_i(batch, N, g + 1);

    float acc[HD];
    #pragma unroll
    for (int j = 0; j < HD; ++j) acc[j] = 0.f;

    for (int n = lo + tid; n < hi; n += 256) {
        const float* xp = x_out + (size_t)n * 16;
        #pragma unroll
        for (int j = 0; j < HD; ++j) acc[j] += xp[j];
    }
    #pragma unroll
    for (int j = 0; j < HD; ++j) red[tid * 15 + j] = acc[j];
    __syncthreads();

    for (int s = 128; s >= 1; s >>= 1) {
        if (tid < s) {
            #pragma unroll
            for (int j = 0; j < HD; ++j) red[tid * 15 + j] += red[(tid + s) * 15 + j];
        }
        __syncthreads();
    }

    if (tid == 0) {
        float invc = 1.0f / fmaxf((float)(hi - lo), 1.0f);
        float gm[HD];
        #pragma unroll
        for (int j = 0; j < HD; ++j) gm[j] = red[j] * invc;
        float h[HD];
        #pragma unroll
        for (int j = 0; j < HD; ++j) {
            float v = bg1[j];
            #pragma unroll
            for (int k = 0; k < HD; ++k) v = fmaf(gm[k], Wg1[k*HD+j], v);
            h[j] = fmaxf(v, 0.f);
        }
        #pragma unroll
        for (int o = 0; o < NOUT; ++o) {
            float v = bg2[o];
            #pragma unroll
            for (int k = 0; k < HD; ++k) v = fmaf(h[k], Wg2[k*NOUT+o], v);
            out[g * NOUT + o] = v;
        }
    }
}

extern "C" void kernel_launch(void* const* d_in, const int* in_sizes, int n_in,
                              void* d_out, int out_size, void* d_ws, size_t ws_size,
                              hipStream_t stream) {
    const int N = NN, E = EE, G = GG;

    const float4* x     = (const float4*)d_in[0];
    const int*    eidx  = (const int*)d_in[1];
    const int*    batch = (const int*)d_in[2];
    const float*  We1  = (const float*)d_in[3];
    const float*  be1  = (const float*)d_in[4];
    const float*  We2  = (const float*)d_in[5];
    const float*  be2  = (const float*)d_in[6];
    const float*  Wn11 = (const float*)d_in[7];
    const float*  bn11 = (const float*)d_in[8];
    const float*  Wn12 = (const float*)d_in[9];
    const float*  bn12 = (const float*)d_in[10];
    const float*  Wn21 = (const float*)d_in[11];
    const float*  bn21 = (const float*)d_in[12];
    const float*  Wn22 = (const float*)d_in[13];
    const float*  bn22 = (const float*)d_in[14];
    const float*  Wg1  = (const float*)d_in[15];
    const float*  bg1  = (const float*)d_in[16];
    const float*  Wg2  = (const float*)d_in[17];
    const float*  bg2  = (const float*)d_in[18];

    const int* row = eidx;       // edge_index[0]
    const int* col = eidx + E;   // edge_index[1]

    // workspace layout (bytes) — every buffer fully written before read, no memsets:
    //   ghist  @ 0         NCELL ints   (1,600,512)
    //   excl   @ 2,097,152 NCELL ints   (1,600,512)
    //   btot   @ 3,800,064 NBSCAN ints  (784)
    //   Cfold  @ 3,801,088 (784)
    //   bfold  @ 3,802,112 (56)
    //   srcdst @ 4,194,304 E int2       (25,600,000) -> ends 29,794,304
    //   x_out  @ 29,794,304 N*16 floats (12,800,000) -> ends 42,594,304
    char*  ws     = (char*)d_ws;
    int*   ghist  = (int*)(ws + 0);
    int*   excl   = (int*)(ws + 2097152);
    int*   btot   = (int*)(ws + 3800064);
    float* Cfold  = (float*)(ws + 3801088);
    float* bfold  = (float*)(ws + 3802112);
    int2*  srcdst = (int2*)(ws + 4194304);
    float* x_out  = (float*)(ws + 29794304);

    dim3 blk(256);
    fold_kernel<<<dim3(1), blk, 0, stream>>>(We2, be2, Wn11, bn11, Cfold, bfold);

    histA<<<dim3(NBLKA), blk, 0, stream>>>(col, ghist);
    scan1_kernel<<<dim3(NBSCAN), dim3(SBS), 0, stream>>>(ghist, excl, btot, NCELL);
    scan2_kernel<<<dim3(1), blk, 0, stream>>>(btot, NBSCAN);
    scatterA<<<dim3(NBLKA), blk, 0, stream>>>(row, col, excl, btot, srcdst);

    bucket_kernel<<<dim3(NBIN), blk, 0, stream>>>(
        x, srcdst, excl, btot,
        We1, be1, Wn11, Cfold, bfold,
        Wn12, bn12, Wn21, bn21, Wn22, bn22,
        x_out, N, E);

    graph_kernel<<<dim3(G), blk, 0, stream>>>(x_out, batch, Wg1, bg1, Wg2, bg2,
                                              (float*)d_out, N, G);
}